// Round 8
// baseline (1129.229 us; speedup 1.0000x reference)
//
#include <hip/hip_runtime.h>
#include <math.h>

constexpr int NN   = 50000;
constexpr int NE   = 800000;
constexpr int NE2  = NE + NN;
constexpr int NREL = 4;
constexpr int NB   = (NN + 255) / 256;   // scan blocks

typedef __attribute__((ext_vector_type(8))) short bfrag;     // 8 bf16 (4 VGPRs)
typedef __attribute__((ext_vector_type(4))) float floatx4;   // MFMA acc

__device__ inline unsigned short bf16_rne(float x) {
  unsigned u = __float_as_uint(x);
  unsigned r = (u + 0x7FFFu + ((u >> 16) & 1u)) >> 16;
  return (unsigned short)r;
}
__device__ inline float bf2f(unsigned short h) {
  return __uint_as_float((unsigned)h << 16);
}
__device__ inline void split2(float x, unsigned short& h, unsigned short& l) {
  h = bf16_rne(x);
  l = bf16_rne(x - bf2f(h));
}
__device__ inline unsigned f2key(float f) {
  unsigned b = __float_as_uint(f);
  return (b & 0x80000000u) ? ~b : (b | 0x80000000u);
}
__device__ inline float key2f(unsigned k) {
  unsigned b = (k & 0x80000000u) ? (k & 0x7FFFFFFFu) : ~k;
  return __uint_as_float(b);
}

// ---------------------------------------------------------------------------
__global__ void k_counts(const int* __restrict__ src, const int* __restrict__ dst,
                         const int* __restrict__ et, int* deg, int* cntrel) {
  int e = blockIdx.x * blockDim.x + threadIdx.x;
  if (e < NE) {
    int d = dst[e];
    atomicAdd(&deg[d], 1);
    atomicAdd(&cntrel[d * NREL + et[e]], 1);
  }
}

__global__ void k_scan1(const int* __restrict__ deg, int* bsum) {
  __shared__ int sm[256];
  int i = blockIdx.x * 256 + threadIdx.x;
  sm[threadIdx.x] = (i < NN) ? deg[i] : 0;
  __syncthreads();
  for (int s = 128; s; s >>= 1) {
    if (threadIdx.x < s) sm[threadIdx.x] += sm[threadIdx.x + s];
    __syncthreads();
  }
  if (threadIdx.x == 0) bsum[blockIdx.x] = sm[0];
}
__global__ void k_scan2(const int* __restrict__ bsum, int* boff, int* rowptr) {
  if (threadIdx.x == 0 && blockIdx.x == 0) {
    int acc = 0;
    for (int b = 0; b < NB; ++b) { boff[b] = acc; acc += bsum[b]; }
    rowptr[NN] = NE;
  }
}
__global__ void k_scan3(const int* __restrict__ deg, const int* __restrict__ boff,
                        int* rowptr) {
  __shared__ int sm[256];
  int i = blockIdx.x * 256 + threadIdx.x;
  int v = (i < NN) ? deg[i] : 0;
  sm[threadIdx.x] = v;
  __syncthreads();
  for (int s = 1; s < 256; s <<= 1) {
    int t = (threadIdx.x >= s) ? sm[threadIdx.x - s] : 0;
    __syncthreads();
    sm[threadIdx.x] += t;
    __syncthreads();
  }
  if (i < NN) rowptr[i] = boff[blockIdx.x] + sm[threadIdx.x] - v;  // exclusive
}

__global__ void k_fill(const int* __restrict__ src, const int* __restrict__ dst,
                       const int* __restrict__ et, const int* __restrict__ rowptr,
                       int* cursor, int* srcs, int* ets) {
  int e = blockIdx.x * blockDim.x + threadIdx.x;
  if (e >= NE) return;
  int d = dst[e];
  int pos = rowptr[d] + atomicAdd(&cursor[d], 1);
  srcs[pos] = src[e];
  ets[pos]  = et[e];
}

// ---------------------------------------------------------------------------
// weight packing into MFMA fragment order (bf16), once per launch.
#define PK_N 14
__device__ __constant__ const int PK_BASE[PK_N]  = {0,1,2,3,4,4,5,5,5,5,6,7,7,7};
__device__ __constant__ const int PK_EOFF[PK_N]  = {0,0,0,0,0,256,0,32768,65536,98304,0,0,32768,65536};
__device__ __constant__ const int PK_K[PK_N]     = {128,128,256,256,256,256,256,256,256,256,256,256,256,128};
__device__ __constant__ const int PK_LDB[PK_N]   = {256,256,256,256,512,512,128,128,128,128,128,128,128,128};
__device__ __constant__ const int PK_START[PK_N] = {0,4096,8192,16384,24576,32768,40960,45056,49152,53248,57344,61440,65536,69632};
constexpr int PK_TOTAL = 71680;
constexpr int BF_S1WL = 0,     BF_S1WR = 4096,  BF_S2WL = 8192,  BF_S2WR = 16384;
constexpr int BF_GATW0 = 24576, BF_GATW1 = 32768, BF_WREL = 40960, BF_WROOT = 57344;
constexpr int BF_FW0 = 61440,  BF_FW1 = 65536,  BF_FW2 = 69632;

__global__ void k_pack(const float* b0, const float* b1, const float* b2, const float* b3,
                       const float* b4, const float* b5, const float* b6, const float* b7,
                       unsigned short* __restrict__ Bh) {
  int f = blockIdx.x * 256 + threadIdx.x;
  if (f >= PK_TOTAL) return;
  int m = 0;
#pragma unroll
  for (int i = 1; i < PK_N; ++i) if (f >= PK_START[i]) m = i;
  const float* bases[8] = {b0,b1,b2,b3,b4,b5,b6,b7};
  int lf = f - PK_START[m];
  int K = PK_K[m], ldb = PK_LDB[m];
  int Kq16 = K << 1;
  int ntile = lf / Kq16;
  int rem = lf - ntile * Kq16;
  int kq = rem >> 4, c = rem & 15;
  const float* sp = bases[PK_BASE[m]] + PK_EOFF[m] + (size_t)(kq * 8) * ldb + ntile * 16 + c;
#pragma unroll
  for (int j = 0; j < 8; ++j)
    Bh[(size_t)f * 8 + j] = bf16_rne(sp[(size_t)j * ldb]);
}

// x -> hi/lo planes
__global__ void k_split(const float* __restrict__ x, unsigned short* __restrict__ xh,
                        unsigned short* __restrict__ xl, long total4) {
  long i = (long)blockIdx.x * blockDim.x + threadIdx.x;
  if (i >= total4) return;
  float4 v = ((const float4*)x)[i];
  ushort4 h, l;
  split2(v.x, h.x, l.x); split2(v.y, h.y, l.y);
  split2(v.z, h.z, l.z); split2(v.w, h.w, l.w);
  ((ushort4*)xh)[i] = h;
  ((ushort4*)xl)[i] = l;
}

// ---------------------------------------------------------------------------
// CSR mean, 128 ch, hi-plane input, unroll 2
__global__ void k_mean128p(const unsigned short* __restrict__ ih, const int* __restrict__ rowptr,
                           const int* __restrict__ srcs,
                           unsigned short* __restrict__ oh, unsigned short* __restrict__ ol) {
  int node = blockIdx.x * 4 + (threadIdx.x >> 6);
  int lane = threadIdx.x & 63;
  if (node >= NN) return;
  int p0 = rowptr[node], p1 = rowptr[node + 1];
  float2 acc = make_float2(0.f, 0.f);
  int p = p0;
  for (; p + 1 < p1; p += 2) {
    int s0 = srcs[p], s1 = srcs[p + 1];
    ushort2 v0 = *(const ushort2*)(ih + ((size_t)s0 << 7) + lane * 2);
    ushort2 v1 = *(const ushort2*)(ih + ((size_t)s1 << 7) + lane * 2);
    acc.x += bf2f(v0.x) + bf2f(v1.x);
    acc.y += bf2f(v0.y) + bf2f(v1.y);
  }
  if (p < p1) {
    int s0 = srcs[p];
    ushort2 v0 = *(const ushort2*)(ih + ((size_t)s0 << 7) + lane * 2);
    acc.x += bf2f(v0.x); acc.y += bf2f(v0.y);
  }
  float inv = (p1 > p0) ? 1.0f / (float)(p1 - p0) : 0.0f;
  ushort2 h, l;
  split2(acc.x * inv, h.x, l.x); split2(acc.y * inv, h.y, l.y);
  size_t o = ((size_t)node << 7) + lane * 2;
  *(ushort2*)(oh + o) = h;
  *(ushort2*)(ol + o) = l;
}

// CSR mean, 256 ch, hi-plane input, unroll 2
__global__ void k_mean256p(const unsigned short* __restrict__ ih, const int* __restrict__ rowptr,
                           const int* __restrict__ srcs,
                           unsigned short* __restrict__ oh, unsigned short* __restrict__ ol) {
  int node = blockIdx.x * 4 + (threadIdx.x >> 6);
  int lane = threadIdx.x & 63;
  if (node >= NN) return;
  int p0 = rowptr[node], p1 = rowptr[node + 1];
  float4 acc = make_float4(0.f, 0.f, 0.f, 0.f);
  int p = p0;
  for (; p + 1 < p1; p += 2) {
    int s0 = srcs[p], s1 = srcs[p + 1];
    ushort4 v0 = *(const ushort4*)(ih + ((size_t)s0 << 8) + lane * 4);
    ushort4 v1 = *(const ushort4*)(ih + ((size_t)s1 << 8) + lane * 4);
    acc.x += bf2f(v0.x) + bf2f(v1.x);
    acc.y += bf2f(v0.y) + bf2f(v1.y);
    acc.z += bf2f(v0.z) + bf2f(v1.z);
    acc.w += bf2f(v0.w) + bf2f(v1.w);
  }
  if (p < p1) {
    int s0 = srcs[p];
    ushort4 v0 = *(const ushort4*)(ih + ((size_t)s0 << 8) + lane * 4);
    acc.x += bf2f(v0.x); acc.y += bf2f(v0.y);
    acc.z += bf2f(v0.z); acc.w += bf2f(v0.w);
  }
  float inv = (p1 > p0) ? 1.0f / (float)(p1 - p0) : 0.0f;
  ushort4 h, l;
  split2(acc.x * inv, h.x, l.x); split2(acc.y * inv, h.y, l.y);
  split2(acc.z * inv, h.z, l.z); split2(acc.w * inv, h.w, l.w);
  size_t o = ((size_t)node << 8) + lane * 4;
  *(ushort4*)(oh + o) = h;
  *(ushort4*)(ol + o) = l;
}

// ---------------------------------------------------------------------------
// split-A x bf16-B MFMA GEMM, DIRECT fragment loads (no LDS, no barriers).
// A planes are row-major (lane reads its own fragment rows); B is packed in
// fragment order (wave-contiguous 1KB loads). 2 MFMAs per tile pair.
__global__ __launch_bounds__(256)
void k_gemm_mfma(const unsigned short* __restrict__ Bph,
                 const unsigned short* A0h, const unsigned short* A0l, int lda0, int bf0, int K0,
                 const unsigned short* A1h, const unsigned short* A1l, int lda1, int bf1, int K1,
                 const unsigned short* A2h, const unsigned short* A2l, int lda2, int bf2, int K2,
                 const float* __restrict__ bias, float* Cf,
                 unsigned short* Ch, unsigned short* Cl,
                 int M, int Nc, float scale, int do_relu, int zsB, long zsC)
{
  const int tid  = threadIdx.x;
  const int lane = tid & 63;
  const int wv   = tid >> 6;
  const int wm   = wv >> 1, wn = wv & 1;
  const int row0 = blockIdx.y * 128;
  const int col0 = blockIdx.x * 128;
  if (zsB) {
    bf0 += blockIdx.z * zsB;
    long zc = (long)blockIdx.z * zsC;
    if (Cf) Cf += zc;
    if (Ch) { Ch += zc; if (Cl) Cl += zc; }
  }

  floatx4 acc[4][4];
#pragma unroll
  for (int i = 0; i < 4; ++i)
#pragma unroll
    for (int j = 0; j < 4; ++j) acc[i][j] = 0;

  const int lm = lane & 15;      // row-within-16 / col-within-16
  const int lq = lane >> 4;      // k-quad

  const unsigned short* Aharr[3] = {A0h, A1h, A2h};
  const unsigned short* Alarr[3] = {A0l, A1l, A2l};
  const int ldaArr[3] = {lda0, lda1, lda2};
  const int bfArr[3]  = {bf0, bf1, bf2};
  const int Karr[3]   = {K0, K1, K2};

  for (int p = 0; p < 3; ++p) {
    const int K = Karr[p];
    if (K == 0) continue;
    const int lda = ldaArr[p];
    const int Kq16 = K << 1;
    // per-mt A fragment base pointers (row clamped; rows >= M never stored)
    const unsigned short* Ahp[4];
    const unsigned short* Alp[4];
#pragma unroll
    for (int mt = 0; mt < 4; ++mt) {
      int row = row0 + (wm * 4 + mt) * 16 + lm;
      row = row < M ? row : (M - 1);
      Ahp[mt] = Aharr[p] + (size_t)row * lda + lq * 8;
      Alp[mt] = Alarr[p] + (size_t)row * lda + lq * 8;
    }
    // per-nt B fragment base pointers (contiguous across lanes)
    const unsigned short* Bp[4];
#pragma unroll
    for (int nt = 0; nt < 4; ++nt) {
      int fb = bfArr[p] + (col0 >> 4) * Kq16 + (wn * 4 + nt) * Kq16 + lane;
      Bp[nt] = Bph + (size_t)fb * 8;
    }

    for (int kt = 0; kt < K; kt += 32) {
      bfrag afh[4], afl[4], bfh[4];
#pragma unroll
      for (int mt = 0; mt < 4; ++mt) {
        afh[mt] = *(const bfrag*)(Ahp[mt] + kt);
        afl[mt] = *(const bfrag*)(Alp[mt] + kt);
      }
#pragma unroll
      for (int nt = 0; nt < 4; ++nt)
        bfh[nt] = *(const bfrag*)(Bp[nt] + (size_t)kt * 16);
#pragma unroll
      for (int mt = 0; mt < 4; ++mt)
#pragma unroll
        for (int nt = 0; nt < 4; ++nt) {
          acc[mt][nt] = __builtin_amdgcn_mfma_f32_16x16x32_bf16(afh[mt], bfh[nt], acc[mt][nt], 0, 0, 0);
          acc[mt][nt] = __builtin_amdgcn_mfma_f32_16x16x32_bf16(afl[mt], bfh[nt], acc[mt][nt], 0, 0, 0);
        }
    }
  }

  // epilogue: C/D layout col=lane&15, row=(lane>>4)*4+reg   [m89-verified]
  const int cl = lm;
  const int rq = lq;
#pragma unroll
  for (int mt = 0; mt < 4; ++mt)
#pragma unroll
    for (int r = 0; r < 4; ++r) {
      int row = row0 + wm * 64 + mt * 16 + rq * 4 + r;
      if (row < M) {
#pragma unroll
        for (int nt = 0; nt < 4; ++nt) {
          int colx = col0 + wn * 64 + nt * 16 + cl;
          float v = acc[mt][nt][r] * scale + (bias ? bias[colx] : 0.0f);
          if (do_relu) v = fmaxf(v, 0.0f);
          size_t o = (size_t)row * Nc + colx;
          if (Cf) Cf[o] = v;
          if (Ch) {
            if (Cl) {
              unsigned short h, l; split2(v, h, l);
              Ch[o] = h; Cl[o] = l;
            } else {
              Ch[o] = bf16_rne(v);
            }
          }
        }
      }
    }
}

// ---------------------------------------------------------------------------
// GAT: wt[4][256] = {W@att_s(h0), W@att_s(h1), W@att_d(h0), W@att_d(h1)}
__global__ void k_wtilde(const float* __restrict__ gatW, const float* __restrict__ att_s,
                         const float* __restrict__ att_d, float* __restrict__ wt) {
  int k = threadIdx.x;
  const float* Wr = gatW + (size_t)k * 512;
  float s0 = 0, s1 = 0, d0 = 0, d1 = 0;
  for (int i = 0; i < 256; ++i) {
    float w0 = Wr[i], w1 = Wr[256 + i];
    s0 += w0 * att_s[i];       s1 += w1 * att_s[256 + i];
    d0 += w0 * att_d[i];       d1 += w1 * att_d[256 + i];
  }
  wt[k] = s0; wt[256 + k] = s1; wt[512 + k] = d0; wt[768 + k] = d1;
}

// per-node logits from xs hi plane
__global__ void k_al(const unsigned short* __restrict__ xsh_, const float* __restrict__ wt,
                     float* __restrict__ al_s, float* __restrict__ al_d) {
  int node = blockIdx.x * 4 + (threadIdx.x >> 6);
  int lane = threadIdx.x & 63;
  if (node >= NN) return;
  ushort4 hv = *(const ushort4*)(xsh_ + (size_t)node * 256 + lane * 4);
  float4 v = make_float4(bf2f(hv.x), bf2f(hv.y), bf2f(hv.z), bf2f(hv.w));
  const float4* w = (const float4*)wt;
  float4 a0 = w[lane], a1 = w[64 + lane], a2 = w[128 + lane], a3 = w[192 + lane];
  float s0 = v.x*a0.x + v.y*a0.y + v.z*a0.z + v.w*a0.w;
  float s1 = v.x*a1.x + v.y*a1.y + v.z*a1.z + v.w*a1.w;
  float s2 = v.x*a2.x + v.y*a2.y + v.z*a2.z + v.w*a2.w;
  float s3 = v.x*a3.x + v.y*a3.y + v.z*a3.z + v.w*a3.w;
  for (int off = 32; off; off >>= 1) {
    s0 += __shfl_down(s0, off); s1 += __shfl_down(s1, off);
    s2 += __shfl_down(s2, off); s3 += __shfl_down(s3, off);
  }
  if (lane == 0) {
    al_s[node*2] = s0; al_s[node*2 + 1] = s1;
    al_d[node*2] = s2; al_d[node*2 + 1] = s3;
  }
}

__device__ inline float lrelu(float v) { return v > 0.f ? v : 0.2f * v; }

// edge-parallel per-(dst,head) max of lrelu(al_s[s]+al_d[d]) incl. self-loops
__global__ void k_gat_max(const int* __restrict__ src, const int* __restrict__ dst,
                          const float* __restrict__ als, const float* __restrict__ ald,
                          unsigned* mkey) {
  int e = blockIdx.x * blockDim.x + threadIdx.x;
  if (e >= NE2) return;
  int s, d;
  if (e < NE) { s = src[e]; d = dst[e]; } else { s = d = e - NE; }
  float2 a = *(const float2*)(als + (size_t)s * 2);
  float2 b = *(const float2*)(ald + (size_t)d * 2);
  atomicMax(&mkey[d*2],     f2key(lrelu(a.x + b.x)));
  atomicMax(&mkey[d*2 + 1], f2key(lrelu(a.y + b.y)));
}

// single-pass fused GAT softmax + aggregation (max precomputed), unroll 2
__global__ void k_gat_csr(const unsigned short* __restrict__ xsh_,
                          const int* __restrict__ rowptr, const int* __restrict__ srcs,
                          const float* __restrict__ als, const float* __restrict__ ald,
                          const unsigned* __restrict__ mkey,
                          unsigned short* __restrict__ aggh, unsigned short* __restrict__ aggl) {
  int node = blockIdx.x * 4 + (threadIdx.x >> 6);
  int lane = threadIdx.x & 63;
  if (node >= NN) return;
  int p0 = rowptr[node], p1 = rowptr[node + 1];
  float bd0 = ald[node*2], bd1 = ald[node*2 + 1];
  float m0 = key2f(mkey[node*2]), m1 = key2f(mkey[node*2 + 1]);
  float w0 = __expf(lrelu(als[node*2] + bd0) - m0);
  float w1 = __expf(lrelu(als[node*2 + 1] + bd1) - m1);
  float den0 = w0, den1 = w1;
  ushort4 hv = *(const ushort4*)(xsh_ + (size_t)node * 256 + lane * 4);
  float4 v = make_float4(bf2f(hv.x), bf2f(hv.y), bf2f(hv.z), bf2f(hv.w));
  float4 acc0 = make_float4(w0*v.x, w0*v.y, w0*v.z, w0*v.w);
  float4 acc1 = make_float4(w1*v.x, w1*v.y, w1*v.z, w1*v.w);
  int p = p0;
  for (; p + 1 < p1; p += 2) {
    int s0 = srcs[p], s1 = srcs[p + 1];
    float2 a0 = *(const float2*)(als + (size_t)s0 * 2);
    float2 a1 = *(const float2*)(als + (size_t)s1 * 2);
    ushort4 r0 = *(const ushort4*)(xsh_ + (size_t)s0 * 256 + lane * 4);
    ushort4 r1 = *(const ushort4*)(xsh_ + (size_t)s1 * 256 + lane * 4);
    float e00 = __expf(lrelu(a0.x + bd0) - m0);
    float e01 = __expf(lrelu(a0.y + bd1) - m1);
    float e10 = __expf(lrelu(a1.x + bd0) - m0);
    float e11 = __expf(lrelu(a1.y + bd1) - m1);
    den0 += e00 + e10; den1 += e01 + e11;
    float4 x0 = make_float4(bf2f(r0.x), bf2f(r0.y), bf2f(r0.z), bf2f(r0.w));
    float4 x1 = make_float4(bf2f(r1.x), bf2f(r1.y), bf2f(r1.z), bf2f(r1.w));
    acc0.x += e00*x0.x + e10*x1.x; acc0.y += e00*x0.y + e10*x1.y;
    acc0.z += e00*x0.z + e10*x1.z; acc0.w += e00*x0.w + e10*x1.w;
    acc1.x += e01*x0.x + e11*x1.x; acc1.y += e01*x0.y + e11*x1.y;
    acc1.z += e01*x0.z + e11*x1.z; acc1.w += e01*x0.w + e11*x1.w;
  }
  if (p < p1) {
    int s0 = srcs[p];
    float2 a0 = *(const float2*)(als + (size_t)s0 * 2);
    ushort4 r0 = *(const ushort4*)(xsh_ + (size_t)s0 * 256 + lane * 4);
    float e00 = __expf(lrelu(a0.x + bd0) - m0);
    float e01 = __expf(lrelu(a0.y + bd1) - m1);
    den0 += e00; den1 += e01;
    float4 x0 = make_float4(bf2f(r0.x), bf2f(r0.y), bf2f(r0.z), bf2f(r0.w));
    acc0.x += e00*x0.x; acc0.y += e00*x0.y; acc0.z += e00*x0.z; acc0.w += e00*x0.w;
    acc1.x += e01*x0.x; acc1.y += e01*x0.y; acc1.z += e01*x0.z; acc1.w += e01*x0.w;
  }
  float i0 = 1.0f / fmaxf(den0, 1e-16f);
  float i1 = 1.0f / fmaxf(den1, 1e-16f);
  ushort4 h, l;
  size_t o = (size_t)node * 512 + lane * 4;
  split2(acc0.x*i0, h.x, l.x); split2(acc0.y*i0, h.y, l.y);
  split2(acc0.z*i0, h.z, l.z); split2(acc0.w*i0, h.w, l.w);
  *(ushort4*)(aggh + o) = h; *(ushort4*)(aggl + o) = l;
  split2(acc1.x*i1, h.x, l.x); split2(acc1.y*i1, h.y, l.y);
  split2(acc1.z*i1, h.z, l.z); split2(acc1.w*i1, h.w, l.w);
  *(ushort4*)(aggh + o + 256) = h; *(ushort4*)(aggl + o + 256) = l;
}

// ---------------------------------------------------------------------------
// CSR RGCN aggregation, all 4 relations, xt hi plane, base P3f, unroll 2
__global__ void k_rgcn_csr(const unsigned short* __restrict__ xth,
                           const int* __restrict__ rowptr, const int* __restrict__ srcs,
                           const int* __restrict__ ets, const int* __restrict__ cntrel,
                           const float* __restrict__ P3f,
                           unsigned short* __restrict__ oh, unsigned short* __restrict__ ol) {
  int node = blockIdx.x * 4 + (threadIdx.x >> 6);
  int lane = threadIdx.x & 63;
  if (node >= NN) return;
  int p0 = rowptr[node], p1 = rowptr[node + 1];
  float inv0, inv1, inv2, inv3;
  {
    int c0 = cntrel[node*NREL], c1 = cntrel[node*NREL+1];
    int c2 = cntrel[node*NREL+2], c3 = cntrel[node*NREL+3];
    inv0 = c0 ? 1.0f/(float)c0 : 0.0f;  inv1 = c1 ? 1.0f/(float)c1 : 0.0f;
    inv2 = c2 ? 1.0f/(float)c2 : 0.0f;  inv3 = c3 ? 1.0f/(float)c3 : 0.0f;
  }
  float2 acc = ((const float2*)(P3f + ((size_t)node << 7)))[lane];
  int p = p0;
  for (; p + 1 < p1; p += 2) {
    int s0 = srcs[p], r0 = ets[p];
    int s1 = srcs[p + 1], r1 = ets[p + 1];
    ushort2 v0 = *(const ushort2*)(xth + (((size_t)r0 * NN + s0) << 7) + lane * 2);
    ushort2 v1 = *(const ushort2*)(xth + (((size_t)r1 * NN + s1) << 7) + lane * 2);
    float w0 = (r0 == 0) ? inv0 : (r0 == 1) ? inv1 : (r0 == 2) ? inv2 : inv3;
    float w1 = (r1 == 0) ? inv0 : (r1 == 1) ? inv1 : (r1 == 2) ? inv2 : inv3;
    acc.x += bf2f(v0.x) * w0 + bf2f(v1.x) * w1;
    acc.y += bf2f(v0.y) * w0 + bf2f(v1.y) * w1;
  }
  if (p < p1) {
    int s0 = srcs[p], r0 = ets[p];
    ushort2 v0 = *(const ushort2*)(xth + (((size_t)r0 * NN + s0) << 7) + lane * 2);
    float w0 = (r0 == 0) ? inv0 : (r0 == 1) ? inv1 : (r0 == 2) ? inv2 : inv3;
    acc.x += bf2f(v0.x) * w0;
    acc.y += bf2f(v0.y) * w0;
  }
  ushort2 h, l;
  split2(acc.x, h.x, l.x); split2(acc.y, h.y, l.y);
  size_t o = ((size_t)node << 7) + lane * 2;
  *(ushort2*)(oh + o) = h;
  *(ushort2*)(ol + o) = l;
}

// ---------------------------------------------------------------------------
__global__ void k_norm(float* __restrict__ out) {
  int gw = (int)(((long)blockIdx.x * blockDim.x + threadIdx.x) >> 6);
  int lane = threadIdx.x & 63;
  if (gw >= NN) return;
  float2* row = (float2*)(out + (size_t)gw * 128);
  float2 v = row[lane];
  float ss = v.x*v.x + v.y*v.y;
  for (int off = 32; off; off >>= 1) ss += __shfl_down(ss, off);
  ss = __shfl(ss, 0);
  float inv = 1.0f / fmaxf(sqrtf(ss), 1e-12f);
  row[lane] = make_float2(v.x*inv, v.y*inv);
}

// ---------------------------------------------------------------------------
extern "C" void kernel_launch(void* const* d_in, const int* in_sizes, int n_in,
                              void* d_out, int out_size, void* d_ws, size_t ws_size,
                              hipStream_t stream)
{
  const float* x     = (const float*)d_in[0];
  const int*   ei    = (const int*)d_in[1];
  const int*   etype = (const int*)d_in[2];
  const float* s1Wl  = (const float*)d_in[3];
  const float* s1Wr  = (const float*)d_in[4];
  const float* s1b   = (const float*)d_in[5];
  const float* s2Wl  = (const float*)d_in[6];
  const float* s2Wr  = (const float*)d_in[7];
  const float* s2b   = (const float*)d_in[8];
  const float* gatW  = (const float*)d_in[9];
  const float* att_s = (const float*)d_in[10];
  const float* att_d = (const float*)d_in[11];
  const float* gatb  = (const float*)d_in[12];
  const float* Wrel  = (const float*)d_in[13];
  const float* Wroot = (const float*)d_in[14];
  const float* rgcnb = (const float*)d_in[15];
  const float* fW    = (const float*)d_in[16];
  const float* fb    = (const float*)d_in[17];
  float* out = (float*)d_out;

  const int* src = ei;
  const int* dst = ei + NE;

  char* ws = (char*)d_ws;
  size_t off = 0;
  auto alloc = [&](size_t bytes) -> void* {
    void* p = ws + off;
    off = (off + bytes + 255) & ~(size_t)255;
    return p;
  };
  int*      deg    = (int*)alloc((size_t)NN * 4);
  int*      cntrel = (int*)alloc((size_t)NN * NREL * 4);
  int*      rowptr = (int*)alloc((size_t)(NN + 1) * 4);
  int*      cursor = (int*)alloc((size_t)NN * 4);
  int*      bsum   = (int*)alloc((size_t)NB * 4);
  int*      boff   = (int*)alloc((size_t)NB * 4);
  int*      srcs   = (int*)alloc((size_t)NE * 4);
  int*      ets    = (int*)alloc((size_t)NE * 4);
  float*    al_s   = (float*)alloc((size_t)NN * 2 * 4);
  float*    al_d   = (float*)alloc((size_t)NN * 2 * 4);
  unsigned* mkey   = (unsigned*)alloc((size_t)NN * 2 * 4);
  float*    wt     = (float*)alloc((size_t)4 * 256 * 4);
  unsigned short* PBh = (unsigned short*)alloc((size_t)PK_TOTAL * 8 * 2);
  // 4 x 51.2 MB slabs with strict lifetime overlay (total ws ~215 MB)
  char* SAb = (char*)alloc((size_t)NN * 1024);
  char* SBb = (char*)alloc((size_t)NN * 1024);
  char* SCb = (char*)alloc((size_t)NN * 1024);
  char* SDb = (char*)alloc((size_t)NN * 1024);
  (void)ws_size; (void)in_sizes; (void)n_in; (void)out_size;

  // SlabA: x/m1 planes -> aggh -> P3f + p3 planes
  unsigned short* xh  = (unsigned short*)SAb;
  unsigned short* xl  = xh + (size_t)NN * 128;
  unsigned short* m1h = xl + (size_t)NN * 128;
  unsigned short* m1l = m1h + (size_t)NN * 128;
  unsigned short* aggh = (unsigned short*)SAb;                  // N*512
  float*          P3f  = (float*)SAb;                           // N*128 f32
  unsigned short* p3h  = (unsigned short*)(SAb + (size_t)NN * 512);
  unsigned short* p3l  = p3h + (size_t)NN * 128;
  // SlabB: x1 planes -> aggl -> xt hi (4 relations)
  unsigned short* x1h = (unsigned short*)SBb;
  unsigned short* x1l = x1h + (size_t)NN * 256;
  unsigned short* aggl = (unsigned short*)SBb;                  // N*512
  unsigned short* xth = (unsigned short*)SBb;                   // 4*N*128
  // SlabC: m2 planes -> xg planes
  unsigned short* m2h = (unsigned short*)SCb;
  unsigned short* m2l = m2h + (size_t)NN * 256;
  unsigned short* xgh = (unsigned short*)SCb;
  unsigned short* xgl = xgh + (size_t)NN * 256;
  // SlabD: xs planes (persistent)
  unsigned short* xsh = (unsigned short*)SDb;
  unsigned short* xsl = xsh + (size_t)NN * 256;

  const int NODEB = (NN + 3) / 4;
  const int GY = (NN + 127) / 128;

  // ---- weight packing + CSR build
  k_pack<<<(PK_TOTAL + 255) / 256, 256, 0, stream>>>(s1Wl, s1Wr, s2Wl, s2Wr, gatW, Wrel, Wroot, fW, PBh);
  hipMemsetAsync(deg, 0, (size_t)NN * 4, stream);
  hipMemsetAsync(cntrel, 0, (size_t)NN * NREL * 4, stream);
  hipMemsetAsync(cursor, 0, (size_t)NN * 4, stream);
  k_counts<<<(NE + 255) / 256, 256, 0, stream>>>(src, dst, etype, deg, cntrel);
  k_scan1<<<NB, 256, 0, stream>>>(deg, bsum);
  k_scan2<<<1, 64, 0, stream>>>(bsum, boff, rowptr);
  k_scan3<<<NB, 256, 0, stream>>>(deg, boff, rowptr);
  k_fill<<<(NE + 255) / 256, 256, 0, stream>>>(src, dst, etype, rowptr, cursor, srcs, ets);
  k_split<<<((NN * 128 / 4) + 255) / 256, 256, 0, stream>>>(x, xh, xl, (long)NN * 128 / 4);

  // ---- SAGE1: mean(x hi) -> m1 ; x1 = relu([m1|x]@[Wl;Wr]+b) -> x1 planes
  k_mean128p<<<NODEB, 256, 0, stream>>>(xh, rowptr, srcs, m1h, m1l);
  k_gemm_mfma<<<dim3(2, GY, 1), 256, 0, stream>>>(PBh,
      m1h, m1l, 128, BF_S1WL, 128,  xh, xl, 128, BF_S1WR, 128,  nullptr, nullptr, 0, 0, 0,
      s1b, nullptr, x1h, x1l, NN, 256, 1.0f, 1, 0, 0);

  // ---- SAGE2: mean(x1 hi) -> m2 ; x_sage -> xs planes
  k_mean256p<<<NODEB, 256, 0, stream>>>(x1h, rowptr, srcs, m2h, m2l);
  k_gemm_mfma<<<dim3(2, GY, 1), 256, 0, stream>>>(PBh,
      m2h, m2l, 256, BF_S2WL, 256,  x1h, x1l, 256, BF_S2WR, 256,  nullptr, nullptr, 0, 0, 0,
      s2b, nullptr, xsh, xsl, NN, 256, 1.0f, 1, 0, 0);

  // ---- GAT: logits, edge-parallel max, single-pass fused agg, projection
  k_wtilde<<<1, 256, 0, stream>>>(gatW, att_s, att_d, wt);
  k_al<<<NODEB, 256, 0, stream>>>(xsh, wt, al_s, al_d);
  hipMemsetAsync(mkey, 0, (size_t)NN * 2 * 4, stream);
  k_gat_max<<<(NE2 + 255) / 256, 256, 0, stream>>>(src, dst, al_s, al_d, mkey);
  k_gat_csr<<<NODEB, 256, 0, stream>>>(xsh, rowptr, srcs, al_s, al_d, mkey, aggh, aggl);
  k_gemm_mfma<<<dim3(2, GY, 1), 256, 0, stream>>>(PBh,
      aggh, aggl, 512, BF_GATW0, 256,  aggh + 256, aggl + 256, 512, BF_GATW1, 256,
      nullptr, nullptr, 0, 0, 0,
      gatb, nullptr, xgh, xgl, NN, 256, 0.5f, 1, 0, 0);

  // ---- RGCN: root -> P3f ; all 4 relation transforms (z-batch) -> xt hi ; agg
  k_gemm_mfma<<<dim3(1, GY, 1), 256, 0, stream>>>(PBh,
      xgh, xgl, 256, BF_WROOT, 256,  nullptr, nullptr, 0, 0, 0,  nullptr, nullptr, 0, 0, 0,
      rgcnb, P3f, nullptr, nullptr, NN, 128, 1.0f, 0, 0, 0);
  k_gemm_mfma<<<dim3(1, GY, NREL), 256, 0, stream>>>(PBh,
      xgh, xgl, 256, BF_WREL, 256,  nullptr, nullptr, 0, 0, 0,  nullptr, nullptr, 0, 0, 0,
      nullptr, nullptr, xth, nullptr, NN, 128, 1.0f, 0, 4096, (long)NN * 128);
  k_rgcn_csr<<<NODEB, 256, 0, stream>>>(xth, rowptr, srcs, ets, cntrel, P3f, p3h, p3l);

  // ---- fusion + L2 normalize
  k_gemm_mfma<<<dim3(1, GY, 1), 256, 0, stream>>>(PBh,
      xsh, xsl, 256, BF_FW0, 256,  xgh, xgl, 256, BF_FW1, 256,  p3h, p3l, 128, BF_FW2, 128,
      fb, out, nullptr, nullptr, NN, 128, 1.0f, 0, 0, 0);
  k_norm<<<(NN + 3) / 4, 256, 0, stream>>>(out);
}